// Round 2
// baseline (1611.121 us; speedup 1.0000x reference)
//
#include <hip/hip_runtime.h>

// Depthwise 9x9 cross-correlation, single shared kernel, stride 1, pad 4.
// X: (32,64,256,256) fp32  -> 2048 independent 256x256 planes
// K: (1,1,9,9) fp32
// out: (32,64,256,256) fp32
//
// v3: NO LDS. Lane l owns a 4-wide column strip (x0 = 4*l); a wave of 64
// lanes covers the full 256-col row. Each of 4 waves per block handles a
// 64-row band of one plane. Per 4-output-row chunk, each lane reads its
// 12-float window (3x global_load_dwordx4, coalesced across lanes, L1-hot
// due to 16B-shifted overlap) for 12 input rows and does 1296 FMAs.
// No barriers, no staging, no LDS bank conflicts. FMA order identical to
// v1/v2 -> bit-identical results.

#define CONV_H 256
#define CONV_W 256
#define NPLANES 2048

__global__ __launch_bounds__(256)
void conv9x9_kernel(const float* __restrict__ X,
                    const float* __restrict__ K,
                    float* __restrict__ out)
{
    const int tid  = threadIdx.x;
    const int lane = tid & 63;
    const int wv   = tid >> 6;                 // wave index: band 0..3
    const int plane = blockIdx.x;              // 2048 blocks

    const int x0 = lane << 2;                  // 0..252, strip start col
    // wave-uniform band start row, forced into an SGPR so the gy bounds
    // checks below compile to scalar branches (no exec-mask games)
    const int y0 = __builtin_amdgcn_readfirstlane(wv << 6);

    const float* __restrict__ Xp = X + (size_t)plane * (CONV_H * CONV_W);
    float* __restrict__ Op       = out + (size_t)plane * (CONV_H * CONV_W);

    // 81 wave-uniform weights -> scalarized to SGPRs by the compiler
    float kw[81];
#pragma unroll
    for (int i = 0; i < 81; ++i) kw[i] = K[i];

    // Horizontal window [x0-4, x0+8): three aligned float4 loads at
    // x0-4, x0, x0+4. Edge lanes clamp the address (stay in-bounds) and
    // zero the pad values via a hoisted 0/1 mask multiply.
    const int   offA = (x0 == 0)   ? 0   : (x0 - 4);
    const int   offC = (x0 == 252) ? 248 : (x0 + 4);
    const float mL   = (x0 == 0)   ? 0.f : 1.f;
    const float mR   = (x0 == 252) ? 0.f : 1.f;

    for (int c = 0; c < 16; ++c) {             // 16 chunks of 4 output rows
        const int oy = y0 + (c << 2);
        float acc[4][4] = {{0.f}};

#pragma unroll
        for (int r = 0; r < 12; ++r) {         // input rows oy-4 .. oy+7
            const int gy = oy - 4 + r;         // scalar (y0,c,r all uniform)
            float rowv[12];
            if ((unsigned)gy < CONV_H) {       // wave-uniform branch
                const float* rb = Xp + gy * CONV_W;
                const float4 a = *reinterpret_cast<const float4*>(rb + offA);
                const float4 b = *reinterpret_cast<const float4*>(rb + x0);
                const float4 d = *reinterpret_cast<const float4*>(rb + offC);
                rowv[0] = a.x * mL; rowv[1] = a.y * mL;
                rowv[2] = a.z * mL; rowv[3] = a.w * mL;
                rowv[4] = b.x; rowv[5] = b.y; rowv[6] = b.z; rowv[7] = b.w;
                rowv[8] = d.x * mR; rowv[9] = d.y * mR;
                rowv[10] = d.z * mR; rowv[11] = d.w * mR;
            } else {
#pragma unroll
                for (int j = 0; j < 12; ++j) rowv[j] = 0.f;
            }

#pragma unroll
            for (int i = 0; i < 4; ++i) {
                const int u = r - i;           // kernel row; constant-folded
                if (u >= 0 && u < 9) {
#pragma unroll
                    for (int v = 0; v < 9; ++v) {
                        const float w = kw[u * 9 + v];
#pragma unroll
                        for (int j = 0; j < 4; ++j)
                            acc[i][j] = fmaf(rowv[v + j], w, acc[i][j]);
                    }
                }
            }
        }

        float* op = Op + (size_t)oy * CONV_W + x0;
#pragma unroll
        for (int i = 0; i < 4; ++i) {
            *reinterpret_cast<float4*>(op + i * CONV_W) =
                make_float4(acc[i][0], acc[i][1], acc[i][2], acc[i][3]);
        }
    }
}

extern "C" void kernel_launch(void* const* d_in, const int* in_sizes, int n_in,
                              void* d_out, int out_size, void* d_ws, size_t ws_size,
                              hipStream_t stream) {
    const float* X = (const float*)d_in[0];
    const float* K = (const float*)d_in[1];
    float* out = (float*)d_out;

    conv9x9_kernel<<<NPLANES, 256, 0, stream>>>(X, K, out);
}

// Round 3
// 990.788 us; speedup vs baseline: 1.6261x; 1.6261x over previous
//
#include <hip/hip_runtime.h>

// Depthwise 9x9 cross-correlation, single shared kernel, stride 1, pad 4.
// X: (32,64,256,256) fp32  -> 2048 independent 256x256 planes
// K: (1,1,9,9) fp32
// out: (32,64,256,256) fp32
//
// v4: rolling shift-register accumulator, no LDS, no barriers.
// Lane l owns a 4-wide column strip (x0 = 4*l); a 64-lane wave covers the
// full 256-col width. Each of 4 waves per block walks a 64-row band of one
// plane top-to-bottom. Per input row: 3 prefetched global_load_dwordx4
// (coalesced, L1/L2-hot), 324 FMAs spread over 9 in-flight output rows
// (acc[9][4]), then acc[0] retires as a completed output row and the
// register file shifts. 3 loads per output row (vs 9 in v1/v3), zero
// steady-state branches, zero LDS traffic.

#define CONV_H 256
#define CONV_W 256
#define NPLANES 2048

__global__ __launch_bounds__(256)
void conv9x9_kernel(const float* __restrict__ X,
                    const float* __restrict__ K,
                    float* __restrict__ out)
{
    const int tid  = threadIdx.x;
    const int lane = tid & 63;
    const int wv   = tid >> 6;                  // band index 0..3
    const int plane = blockIdx.x;               // 2048 blocks

    const int x0 = lane << 2;                   // strip start col, 0..252
    const int B0 = __builtin_amdgcn_readfirstlane(wv << 6);  // band row

    const float* __restrict__ Xp = X + (size_t)plane * (CONV_H * CONV_W);
    float* __restrict__ Op       = out + (size_t)plane * (CONV_H * CONV_W);

    // 81 wave-uniform weights -> SGPRs
    float kw[81];
#pragma unroll
    for (int i = 0; i < 81; ++i) kw[i] = K[i];

    // Horizontal window [x0-4, x0+8): three aligned float4 loads.
    // Edge lanes clamp the address in-bounds and zero pad values by mask.
    const int   offA = (x0 == 0)   ? 0   : (x0 - 4);
    const int   offC = (x0 == 252) ? 248 : (x0 + 4);
    const float mL   = (x0 == 0)   ? 0.f : 1.f;
    const float mR   = (x0 == 252) ? 0.f : 1.f;

    // acc[k] accumulates output row o = g - 4 + k while processing input
    // row g. After row g's FMAs, acc[0] (o = g-4) is complete.
    float acc[9][4];
#pragma unroll
    for (int k = 0; k < 9; ++k)
#pragma unroll
        for (int j = 0; j < 4; ++j) acc[k][j] = 0.f;

    // Valid input-row range for this band (zero-pad rows contribute zero,
    // so they are simply skipped; partial sums for out-of-band rows retire
    // unstored through the shift register).
    const int g_lo = (B0 == 0) ? 0 : (B0 - 4);
    const int g_hi = (B0 + 67 < CONV_H) ? (B0 + 67) : (CONV_H - 1);
    const int g_store = B0 + 4;                 // first g that stores

    // prime the one-row-ahead prefetch
    const float* rb0 = Xp + g_lo * CONV_W;
    float4 a = *reinterpret_cast<const float4*>(rb0 + offA);
    float4 b = *reinterpret_cast<const float4*>(rb0 + x0);
    float4 d = *reinterpret_cast<const float4*>(rb0 + offC);

#pragma unroll 2
    for (int g = g_lo; g <= g_hi; ++g) {
        // ---- prefetch next row (clamped; 324 FMAs of latency slack) ----
        const int gn = (g < g_hi) ? (g + 1) : g_hi;
        const float* rn = Xp + gn * CONV_W;
        const float4 a2 = *reinterpret_cast<const float4*>(rn + offA);
        const float4 b2 = *reinterpret_cast<const float4*>(rn + x0);
        const float4 d2 = *reinterpret_cast<const float4*>(rn + offC);

        // ---- assemble 12-float window for row g ----
        float rowv[12];
        rowv[0] = a.x * mL; rowv[1] = a.y * mL;
        rowv[2] = a.z * mL; rowv[3] = a.w * mL;
        rowv[4] = b.x; rowv[5] = b.y; rowv[6] = b.z; rowv[7] = b.w;
        rowv[8] = d.x * mR; rowv[9] = d.y * mR;
        rowv[10] = d.z * mR; rowv[11] = d.w * mR;

        // ---- 324 FMAs: row g feeds output rows o = g-4+k with u = 8-k ----
#pragma unroll
        for (int k = 0; k < 9; ++k) {
            const int u = 8 - k;
#pragma unroll
            for (int v = 0; v < 9; ++v) {
                const float w = kw[u * 9 + v];
#pragma unroll
                for (int j = 0; j < 4; ++j)
                    acc[k][j] = fmaf(rowv[v + j], w, acc[k][j]);
            }
        }

        // ---- retire completed output row o = g-4 (uniform branch) ----
        if (g >= g_store) {
            float* op = Op + (size_t)(g - 4) * CONV_W + x0;
            *reinterpret_cast<float4*>(op) =
                make_float4(acc[0][0], acc[0][1], acc[0][2], acc[0][3]);
        }

        // ---- shift the accumulator window down one row ----
#pragma unroll
        for (int k = 0; k < 8; ++k)
#pragma unroll
            for (int j = 0; j < 4; ++j) acc[k][j] = acc[k + 1][j];
#pragma unroll
        for (int j = 0; j < 4; ++j) acc[8][j] = 0.f;

        a = a2; b = b2; d = d2;
    }

    // ---- drain (bottom band only): rows whose inputs ended at row 255 ----
    for (int o = g_hi - 3; o < B0 + 64; ++o) {
        float* op = Op + (size_t)o * CONV_W + x0;
        *reinterpret_cast<float4*>(op) =
            make_float4(acc[0][0], acc[0][1], acc[0][2], acc[0][3]);
#pragma unroll
        for (int k = 0; k < 8; ++k)
#pragma unroll
            for (int j = 0; j < 4; ++j) acc[k][j] = acc[k + 1][j];
    }
}

extern "C" void kernel_launch(void* const* d_in, const int* in_sizes, int n_in,
                              void* d_out, int out_size, void* d_ws, size_t ws_size,
                              hipStream_t stream) {
    const float* X = (const float*)d_in[0];
    const float* K = (const float*)d_in[1];
    float* out = (float*)d_out;

    conv9x9_kernel<<<NPLANES, 256, 0, stream>>>(X, K, out);
}